// Round 1
// baseline (743.216 us; speedup 1.0000x reference)
//
#include <hip/hip_runtime.h>

#define THREADS 256

// Generic split-K / split-H matvec with atomic accumulation.
//   y_p[n, k] += sum_{h in slice} relu_opt(x_p[n,h] + x_b[n,h]) * W[n, h, k]
// grid = (ktiles, h_slices, experts); block = 256.
// TCOLS columns per block (thread handles 4 via float4), slice_h rows per block.
// x-slice is staged in LDS with bias+ReLU fused on load.
template<int TCOLS, bool RELU, bool HAS_BIAS>
__global__ __launch_bounds__(THREADS) void matvec_k(
    const float* __restrict__ xp, const float* __restrict__ xb,
    const float* __restrict__ W, float* __restrict__ yp,
    int K, int slice_h,
    long x_stride, long xb_stride, long w_stride, long y_stride)
{
    const int n = blockIdx.z;
    xp += (long)n * x_stride;
    const float* xbn = HAS_BIAS ? (xb + (long)n * xb_stride) : nullptr;
    W  += (long)n * w_stride;
    yp += (long)n * y_stride;

    const int h0 = blockIdx.y * slice_h;
    const int k0 = blockIdx.x * TCOLS;
    constexpr int TPR = TCOLS / 4;       // threads per row
    constexpr int RPI = THREADS / TPR;   // rows processed per iteration
    const int tid    = threadIdx.x;
    const int lane_r = tid % TPR;
    const int row_off = tid / TPR;
    const int c = k0 + 4 * lane_r;

    extern __shared__ float xs[];        // slice_h floats
    for (int i = tid; i < slice_h; i += THREADS) {
        float v = xp[h0 + i];
        if (HAS_BIAS) v += xbn[h0 + i];
        if (RELU) v = fmaxf(v, 0.0f);
        xs[i] = v;
    }
    __syncthreads();

    float ax = 0.f, ay = 0.f, az = 0.f, aw = 0.f;
    const float* Wp = W + (long)(h0 + row_off) * K + c;
    for (int i = row_off; i < slice_h; i += RPI) {
        const float4 w4 = *(const float4*)Wp;
        const float xv = xs[i];
        ax = fmaf(xv, w4.x, ax);
        ay = fmaf(xv, w4.y, ay);
        az = fmaf(xv, w4.z, az);
        aw = fmaf(xv, w4.w, aw);
        Wp += (long)RPI * K;
    }
    atomicAdd(&yp[c + 0], ax);
    atomicAdd(&yp[c + 1], ay);
    atomicAdd(&yp[c + 2], az);
    atomicAdd(&yp[c + 3], aw);
}

// q[a] = W_q[t,t,a] + b_q[t,a];  expkq[n] = sum_a (k_p[n,a]+b_k[n,a]) * q[a]
__global__ __launch_bounds__(256) void qk_kernel(
    const float* __restrict__ kp, const float* __restrict__ bk,
    const float* __restrict__ Wq, const float* __restrict__ bq,
    const int* __restrict__ task, float* __restrict__ ekq)
{
    const int tid = threadIdx.x;
    const int t = task[0];
    __shared__ float qs[256];
    qs[tid] = Wq[((long)t * 10 + t) * 256 + tid] + bq[(long)t * 256 + tid];
    __syncthreads();
    const int wave = tid >> 6, lane = tid & 63;
    for (int n = wave; n < 16; n += 4) {
        float s = 0.f;
        for (int a = lane; a < 256; a += 64)
            s += (kp[n * 256 + a] + bk[n * 256 + a]) * qs[a];
        for (int off = 32; off; off >>= 1) s += __shfl_down(s, off, 64);
        if (lane == 0) ekq[n] = s;
    }
}

// blocks 0..127 : w[n,h] = expkq[n] * relu(e_p[n,h] + b_exp[n,h])   (32768 elems)
// blocks 128..135: res_bias[j] = sum_n expkq[n] * b_v[n,j]          (2048 elems)
__global__ __launch_bounds__(256) void weight_kernel(
    const float* __restrict__ ep, const float* __restrict__ bexp,
    const float* __restrict__ ekq, const float* __restrict__ bv,
    float* __restrict__ wbuf, float* __restrict__ resb)
{
    const int b = blockIdx.x;
    if (b < 128) {
        const int g = b * 256 + threadIdx.x;   // 0..32767
        const int n = g >> 11;
        wbuf[g] = ekq[n] * fmaxf(ep[g] + bexp[g], 0.0f);
    } else {
        const int j = (b - 128) * 256 + threadIdx.x;  // 0..2047
        float s = 0.f;
        #pragma unroll
        for (int n = 0; n < 16; n++) s += ekq[n] * bv[n * 2048 + j];
        resb[j] = s;
    }
}

__global__ __launch_bounds__(256) void out_kernel(
    const float* __restrict__ outp, const float* __restrict__ bl,
    float* __restrict__ o)
{
    const int i = blockIdx.x * 256 + threadIdx.x;  // 512 total
    o[i] = outp[i] + bl[i];
}

extern "C" void kernel_launch(void* const* d_in, const int* in_sizes, int n_in,
                              void* d_out, int out_size, void* d_ws, size_t ws_size,
                              hipStream_t stream)
{
    const float* x    = (const float*)d_in[0];
    const float* W1   = (const float*)d_in[1];
    const float* b1   = (const float*)d_in[2];
    const float* W2   = (const float*)d_in[3];
    const float* b2   = (const float*)d_in[4];
    const float* Wexp = (const float*)d_in[5];
    const float* bexp = (const float*)d_in[6];
    const float* Wv   = (const float*)d_in[7];
    const float* bv   = (const float*)d_in[8];
    const float* Wk   = (const float*)d_in[9];
    const float* bk   = (const float*)d_in[10];
    const float* Wq   = (const float*)d_in[11];
    const float* bq   = (const float*)d_in[12];
    const float* Wt   = (const float*)d_in[13];
    const float* bt   = (const float*)d_in[14];
    const float* Wl   = (const float*)d_in[15];
    const float* bl   = (const float*)d_in[16];
    const int*   task = (const int*)d_in[17];

    // workspace layout (floats)
    float* ws   = (float*)d_ws;
    float* y1p  = ws;           // 2048   @ 0
    float* y2p  = ws + 2048;    // 2048
    float* e_p  = ws + 4096;    // 32768
    float* k_p  = ws + 36864;   // 4096
    float* ekq  = ws + 40960;   // 16
    float* wbuf = ws + 40976;   // 32768
    float* resb = ws + 73744;   // 2048
    float* resp = ws + 75792;   // 2048
    float* t_p  = ws + 77840;   // 2048
    float* outp = ws + 79888;   // 512  -> total 80400 floats

    hipMemsetAsync(d_ws, 0, 80400 * sizeof(float), stream);

    // y1p = x @ W1                          (16 MB)
    matvec_k<1024, false, false><<<dim3(2, 128, 1), THREADS, 16 * 4, stream>>>(
        x, nullptr, W1, y1p, 2048, 16, 0, 0, 0, 0);
    // y2p = relu(y1p + b1) @ W2             (16 MB)
    matvec_k<1024, true, true><<<dim3(2, 128, 1), THREADS, 16 * 4, stream>>>(
        y1p, b1, W2, y2p, 2048, 16, 0, 0, 0, 0);
    // e_p[n] = relu(y2p + b2) @ W_exp[n]    (256 MB)
    matvec_k<1024, true, true><<<dim3(2, 32, 16), THREADS, 64 * 4, stream>>>(
        y2p, b2, Wexp, e_p, 2048, 64, 0, 0, 2048L * 2048, 2048);
    // k_p[n] = relu(e_p[n] + b_exp[n]) @ W_k[n]   (32 MB)
    matvec_k<256, true, true><<<dim3(1, 16, 16), THREADS, 128 * 4, stream>>>(
        e_p, bexp, Wk, k_p, 256, 128, 2048, 2048, 2048L * 256, 256);
    // q, expkq
    qk_kernel<<<1, 256, 0, stream>>>(k_p, bk, Wq, bq, task, ekq);
    // w[n,h], res_bias
    weight_kernel<<<136, 256, 0, stream>>>(e_p, bexp, ekq, bv, wbuf, resb);
    // resp = flatten(w) @ flatten(W_v)      (256 MB)
    matvec_k<1024, false, false><<<dim3(2, 512, 1), THREADS, 64 * 4, stream>>>(
        wbuf, nullptr, Wv, resp, 2048, 64, 0, 0, 0, 0);
    // t_p = (resp + res_bias) @ W_t         (16 MB)
    matvec_k<1024, false, true><<<dim3(2, 128, 1), THREADS, 16 * 4, stream>>>(
        resp, resb, Wt, t_p, 2048, 16, 0, 0, 0, 0);
    // outp = relu(t_p + b_t) @ W_l          (4 MB)
    matvec_k<512, true, true><<<dim3(1, 128, 1), THREADS, 16 * 4, stream>>>(
        t_p, bt, Wl, outp, 512, 16, 0, 0, 0, 0);
    // d_out = outp + b_l
    out_kernel<<<2, 256, 0, stream>>>(outp, bl, (float*)d_out);
}

// Round 3
// 677.037 us; speedup vs baseline: 1.0977x; 1.0977x over previous
//
#include <hip/hip_runtime.h>

#define THREADS 256

// ---------------------------------------------------------------------------
// Split-K / split-H matvec, NO atomics: block (kt, s, n) writes its partial
// row P[n][s][k0..k0+TCOLS) = sum_{h in slice s} x[n,h] * W[n,h,k].
// Rows with x[h]==0 (ReLU zeros) are skipped entirely — never loaded from HBM.
// x must already be fully activated (bias+relu applied by producer).
// ---------------------------------------------------------------------------
template<int TCOLS>
__global__ __launch_bounds__(THREADS) void matvec_k(
    const float* __restrict__ x, const float* __restrict__ W,
    float* __restrict__ P,
    int K, int slice_h, int nslices,
    long x_stride, long w_stride)
{
    const int n = blockIdx.z;
    const float* xn = x + (long)n * x_stride;
    const float* Wn = W + (long)n * w_stride;
    float* Pn = P + ((long)n * nslices + blockIdx.y) * K;

    const int h0 = blockIdx.y * slice_h;
    constexpr int TPR = TCOLS / 4;       // threads per row (float4 each)
    constexpr int RPI = THREADS / TPR;   // rows per iteration
    const int tid = threadIdx.x;
    const int lane_r = tid % TPR;
    const int row_off = tid / TPR;
    const int c = blockIdx.x * TCOLS + 4 * lane_r;

    extern __shared__ char smem[];
    float* xs = (float*)smem;            // slice_h floats
    int*   idx = (int*)(smem + (size_t)slice_h * 4); // slice_h ints
    __shared__ int cnt;

    if (tid == 0) cnt = 0;
    __syncthreads();
    for (int i = tid; i < slice_h; i += THREADS) {
        float v = xn[h0 + i];
        xs[i] = v;
        if (v != 0.0f) { int p = atomicAdd(&cnt, 1); idx[p] = i; }
    }
    __syncthreads();
    const int m = cnt;

    float ax = 0.f, ay = 0.f, az = 0.f, aw = 0.f;
    for (int j = row_off; j < m; j += RPI) {
        const int i = idx[j];
        const float4 w4 = *(const float4*)(Wn + (long)(h0 + i) * K + c);
        const float xv = xs[i];
        ax = fmaf(xv, w4.x, ax);
        ay = fmaf(xv, w4.y, ay);
        az = fmaf(xv, w4.z, az);
        aw = fmaf(xv, w4.w, aw);
    }

    if constexpr (RPI > 1) {
        // Multiple row-offset groups cover the SAME columns: reduce via LDS.
        // (Round-2 bug: direct store here dropped all but one group.)
        __shared__ float red[THREADS * 4];
        red[tid * 4 + 0] = ax; red[tid * 4 + 1] = ay;
        red[tid * 4 + 2] = az; red[tid * 4 + 3] = aw;
        __syncthreads();
        if (row_off == 0) {
            #pragma unroll
            for (int g = 1; g < RPI; g++) {
                const int o = (tid + g * TPR) * 4;
                ax += red[o + 0]; ay += red[o + 1];
                az += red[o + 2]; aw += red[o + 3];
            }
            float4 r; r.x = ax; r.y = ay; r.z = az; r.w = aw;
            *(float4*)(Pn + c) = r;
        }
    } else {
        float4 r; r.x = ax; r.y = ay; r.z = az; r.w = aw;
        *(float4*)(Pn + c) = r;
    }
}

// ---------------------------------------------------------------------------
// Grouped partial-sum reduce + fused bias/activation.
// y[n,col] = act( sum_s P[n][s][col] + bias[n,col] )
// block: 64 cols x 4 slice-groups. grid: (K/64, n)
// ---------------------------------------------------------------------------
template<bool RELU, bool HAS_BIAS>
__global__ __launch_bounds__(THREADS) void reduce_k(
    const float* __restrict__ P, const float* __restrict__ b,
    float* __restrict__ y, int K, int nslices)
{
    const int n = blockIdx.y;
    const int col = blockIdx.x * 64 + (threadIdx.x & 63);
    const int grp = threadIdx.x >> 6;
    const float* Pn = P + (long)n * nslices * K + col;
    float s = 0.f;
    for (int i = grp; i < nslices; i += 4) s += Pn[(long)i * K];
    __shared__ float red[4][64];
    red[grp][threadIdx.x & 63] = s;
    __syncthreads();
    if (threadIdx.x < 64) {
        float t = red[0][threadIdx.x] + red[1][threadIdx.x] +
                  red[2][threadIdx.x] + red[3][threadIdx.x];
        if (HAS_BIAS) t += b[(long)n * K + col];
        if (RELU) t = fmaxf(t, 0.f);
        y[(long)n * K + col] = t;
    }
}

// q[a] = W_q[t,t,a] + b_q[t,a]; bkq[n] = sum_a b_k[n,a]*q[a]
__global__ __launch_bounds__(THREADS) void qprep_k(
    const float* __restrict__ Wq, const float* __restrict__ bq,
    const float* __restrict__ bk, const int* __restrict__ task,
    float* __restrict__ q, float* __restrict__ bkq)
{
    const int tid = threadIdx.x;
    const int t = task[0];
    __shared__ float qs[256];
    float qv = Wq[((long)t * 10 + t) * 256 + tid] + bq[(long)t * 256 + tid];
    qs[tid] = qv; q[tid] = qv;
    __syncthreads();
    const int wave = tid >> 6, lane = tid & 63;
    for (int n = wave; n < 16; n += 4) {
        float s = 0.f;
        for (int a = lane; a < 256; a += 64) s += bk[n * 256 + a] * qs[a];
        for (int o = 32; o; o >>= 1) s += __shfl_down(s, o, 64);
        if (lane == 0) bkq[n] = s;
    }
}

// pkq[n*8+s] = sum_{h in slice s} eact[n,h] * (W_k[n,h,:] . q)   (row-skipped)
__global__ __launch_bounds__(THREADS) void kq_mv_k(
    const float* __restrict__ eact, const float* __restrict__ Wk,
    const float* __restrict__ q, float* __restrict__ pkq)
{
    const int n = blockIdx.y, s = blockIdx.x;
    const int h0 = s * 256;
    const int tid = threadIdx.x;
    __shared__ float xs[256], qs[256];
    __shared__ int idx[256];
    __shared__ int cnt;
    __shared__ float wred[4];
    if (tid == 0) cnt = 0;
    qs[tid] = q[tid];
    __syncthreads();
    float v = eact[n * 2048 + h0 + tid];
    xs[tid] = v;
    if (v != 0.0f) { int p = atomicAdd(&cnt, 1); idx[p] = tid; }
    __syncthreads();
    const int m = cnt;
    const int lane_r = tid & 63, row_off = tid >> 6;
    const float q0 = qs[4 * lane_r], q1 = qs[4 * lane_r + 1];
    const float q2 = qs[4 * lane_r + 2], q3 = qs[4 * lane_r + 3];
    float acc = 0.f;
    for (int j = row_off; j < m; j += 4) {
        const int i = idx[j];
        const float4 w4 = *(const float4*)(Wk + ((long)n * 2048 + h0 + i) * 256 + 4 * lane_r);
        acc += xs[i] * (w4.x * q0 + w4.y * q1 + w4.z * q2 + w4.w * q3);
    }
    for (int o = 32; o; o >>= 1) acc += __shfl_down(acc, o, 64);
    if ((tid & 63) == 0) wred[tid >> 6] = acc;
    __syncthreads();
    if (tid == 0) pkq[n * 8 + s] = wred[0] + wred[1] + wred[2] + wred[3];
}

// blocks 0..127:  wbuf[g] = ekq[n] * eact[g]            (32768 elems)
// blocks 128..135: resb[j] = sum_n ekq[n] * b_v[n,j]    (2048 elems)
// ekq[n] = bkq[n] + sum_s pkq[n*8+s]   (recomputed per block, tiny)
__global__ __launch_bounds__(THREADS) void weight_k(
    const float* __restrict__ eact, const float* __restrict__ pkq,
    const float* __restrict__ bkq, const float* __restrict__ bv,
    float* __restrict__ wbuf, float* __restrict__ resb)
{
    __shared__ float ekqs[16];
    const int tid = threadIdx.x;
    if (tid < 16) {
        float s = bkq[tid];
        #pragma unroll
        for (int j = 0; j < 8; j++) s += pkq[tid * 8 + j];
        ekqs[tid] = s;
    }
    __syncthreads();
    const int b = blockIdx.x;
    if (b < 128) {
        const int g = b * 256 + tid;
        wbuf[g] = ekqs[g >> 11] * eact[g];
    } else {
        const int j = (b - 128) * 256 + tid;
        float s = 0.f;
        #pragma unroll
        for (int n = 0; n < 16; n++) s += ekqs[n] * bv[n * 2048 + j];
        resb[j] = s;
    }
}

extern "C" void kernel_launch(void* const* d_in, const int* in_sizes, int n_in,
                              void* d_out, int out_size, void* d_ws, size_t ws_size,
                              hipStream_t stream)
{
    const float* x    = (const float*)d_in[0];
    const float* W1   = (const float*)d_in[1];
    const float* b1   = (const float*)d_in[2];
    const float* W2   = (const float*)d_in[3];
    const float* b2   = (const float*)d_in[4];
    const float* Wexp = (const float*)d_in[5];
    const float* bexp = (const float*)d_in[6];
    const float* Wv   = (const float*)d_in[7];
    const float* bv   = (const float*)d_in[8];
    const float* Wk   = (const float*)d_in[9];
    const float* bk   = (const float*)d_in[10];
    const float* Wq   = (const float*)d_in[11];
    const float* bq   = (const float*)d_in[12];
    const float* Wt   = (const float*)d_in[13];
    const float* bt   = (const float*)d_in[14];
    const float* Wl   = (const float*)d_in[15];
    const float* bl   = (const float*)d_in[16];
    const int*   task = (const int*)d_in[17];

    // workspace layout (floats) — every location written before read, no init
    float* ws   = (float*)d_ws;
    float* P1   = ws;             // 128*2048 = 262144
    float* y1   = ws + 262144;    // 2048
    float* P2   = ws + 264192;    // 262144
    float* y2   = ws + 526336;    // 2048
    float* Pexp = ws + 528384;    // 16*32*2048 = 1048576
    float* eact = ws + 1576960;   // 32768
    float* q    = ws + 1609728;   // 256
    float* bkq  = ws + 1609984;   // 16
    float* pkq  = ws + 1610000;   // 128
    float* wbuf = ws + 1610128;   // 32768
    float* resb = ws + 1642896;   // 2048
    float* Pv   = ws + 1644944;   // 256*2048 = 524288
    float* resp = ws + 2169232;   // 2048
    float* Pt   = ws + 2171280;   // 262144
    float* tact = ws + 2433424;   // 2048
    float* Pl   = ws + 2435472;   // 64*512 = 32768

    // q / b_k.q prep (independent of main chain — launch first)
    qprep_k<<<1, 256, 0, stream>>>(Wq, bq, bk, task, q, bkq);

    // y1 = relu(x @ W1 + b1)                      (16 MB dense)
    matvec_k<1024><<<dim3(2, 128, 1), THREADS, 16 * 8, stream>>>(
        x, W1, P1, 2048, 16, 128, 0, 0);
    reduce_k<true, true><<<dim3(32, 1), THREADS, 0, stream>>>(P1, b1, y1, 2048, 128);

    // y2 = relu(y1 @ W2 + b2)                     (~8 MB after skip)
    matvec_k<1024><<<dim3(2, 128, 1), THREADS, 16 * 8, stream>>>(
        y1, W2, P2, 2048, 16, 128, 0, 0);
    reduce_k<true, true><<<dim3(32, 1), THREADS, 0, stream>>>(P2, b2, y2, 2048, 128);

    // eact[n] = relu(y2 @ W_exp[n] + b_exp[n])    (~128 MB after skip)
    matvec_k<1024><<<dim3(2, 32, 16), THREADS, 64 * 8, stream>>>(
        y2, Wexp, Pexp, 2048, 64, 32, 0, 2048L * 2048);
    reduce_k<true, true><<<dim3(32, 16), THREADS, 0, stream>>>(Pexp, bexp, eact, 2048, 32);

    // pkq partial scalars of e . (W_k . q)        (~16 MB after skip)
    kq_mv_k<<<dim3(8, 16), THREADS, 0, stream>>>(eact, Wk, q, pkq);

    // wbuf = ekq[n]*eact ; resb = sum_n ekq[n]*b_v[n,:]
    weight_k<<<136, THREADS, 0, stream>>>(eact, pkq, bkq, bv, wbuf, resb);

    // resp = flatten(wbuf) @ flatten(W_v) + resb  (~128 MB after skip)
    matvec_k<1024><<<dim3(2, 256, 1), THREADS, 128 * 8, stream>>>(
        wbuf, Wv, Pv, 2048, 128, 256, 0, 0);
    reduce_k<false, true><<<dim3(32, 1), THREADS, 0, stream>>>(Pv, resb, resp, 2048, 256);

    // tact = relu(resp @ W_t + b_t)               (16 MB dense)
    matvec_k<1024><<<dim3(2, 128, 1), THREADS, 16 * 8, stream>>>(
        resp, Wt, Pt, 2048, 16, 128, 0, 0);
    reduce_k<true, true><<<dim3(32, 1), THREADS, 0, stream>>>(Pt, bt, tact, 2048, 128);

    // d_out = tact @ W_l + b_l                    (~2 MB after skip)
    matvec_k<512><<<dim3(1, 64, 1), THREADS, 32 * 8, stream>>>(
        tact, Wl, Pl, 512, 32, 64, 0, 0);
    reduce_k<false, true><<<dim3(8, 1), THREADS, 0, stream>>>(Pl, bl, (float*)d_out, 512, 64);
}

// Round 4
// 633.025 us; speedup vs baseline: 1.1741x; 1.0695x over previous
//
#include <hip/hip_runtime.h>

#define THREADS 256

// ---------------------------------------------------------------------------
// Plain split-K/split-H matvec (x read raw from global, dense).
// Block (kt, s, n) writes P[n][s][k0..k0+TCOLS).
// ---------------------------------------------------------------------------
template<int TCOLS>
__global__ __launch_bounds__(THREADS) void matvec_k(
    const float* __restrict__ x, const float* __restrict__ W,
    float* __restrict__ P,
    int K, int slice_h, int nslices,
    long x_stride, long w_stride)
{
    const int n = blockIdx.z;
    const float* xn = x + (long)n * x_stride;
    const float* Wn = W + (long)n * w_stride;
    float* Pn = P + ((long)n * nslices + blockIdx.y) * K;

    const int h0 = blockIdx.y * slice_h;
    constexpr int TPR = TCOLS / 4;
    constexpr int RPI = THREADS / TPR;
    const int tid = threadIdx.x;
    const int lane_r = tid % TPR;
    const int row_off = tid / TPR;
    const int c = blockIdx.x * TCOLS + 4 * lane_r;

    extern __shared__ char smem[];
    float* xs = (float*)smem;
    int*   idx = (int*)(smem + (size_t)slice_h * 4);
    __shared__ int cnt;

    if (tid == 0) cnt = 0;
    __syncthreads();
    for (int i = tid; i < slice_h; i += THREADS) {
        float v = xn[h0 + i];
        xs[i] = v;
        if (v != 0.0f) { int p = atomicAdd(&cnt, 1); idx[p] = i; }
    }
    __syncthreads();
    const int m = cnt;

    float ax = 0.f, ay = 0.f, az = 0.f, aw = 0.f;
    for (int j = row_off; j < m; j += RPI) {
        const int i = idx[j];
        const float4 w4 = *(const float4*)(Wn + (long)(h0 + i) * K + c);
        const float xv = xs[i];
        ax = fmaf(xv, w4.x, ax); ay = fmaf(xv, w4.y, ay);
        az = fmaf(xv, w4.z, az); aw = fmaf(xv, w4.w, aw);
    }
    if constexpr (RPI > 1) {
        __shared__ float red[THREADS * 4];
        red[tid * 4 + 0] = ax; red[tid * 4 + 1] = ay;
        red[tid * 4 + 2] = az; red[tid * 4 + 3] = aw;
        __syncthreads();
        if (row_off == 0) {
            #pragma unroll
            for (int g = 1; g < RPI; g++) {
                const int o = (tid + g * TPR) * 4;
                ax += red[o + 0]; ay += red[o + 1];
                az += red[o + 2]; aw += red[o + 3];
            }
            float4 r; r.x = ax; r.y = ay; r.z = az; r.w = aw;
            *(float4*)(Pn + c) = r;
        }
    } else {
        float4 r; r.x = ax; r.y = ay; r.z = az; r.w = aw;
        *(float4*)(Pn + c) = r;
    }
}

// ---------------------------------------------------------------------------
// Matvec with FUSED x-build: x[i] = relu( sum_{s<NSLP} Pprev[.., h0+i] + bias ),
// then zero-skip matvec over W. Removes the standalone reduce kernels.
// SH must divide THREADS.
// ---------------------------------------------------------------------------
template<int TCOLS, int SH, bool RELU>
__global__ __launch_bounds__(THREADS) void matvec_rx(
    const float* __restrict__ Pprev, const float* __restrict__ bias,
    const float* __restrict__ W, float* __restrict__ Pout,
    int K, int nsl_prev, int prev_K, int nsl_out,
    long pprev_stride, long bias_stride, long w_stride)
{
    const int n = blockIdx.z;
    const int h0 = blockIdx.y * SH;
    const float* Pp = Pprev + (long)n * pprev_stride;
    const float* bn = bias + (long)n * bias_stride;
    const float* Wn = W + (long)n * w_stride;
    float* Pn = Pout + ((long)n * nsl_out + blockIdx.y) * K;

    constexpr int G = THREADS / SH;
    const int tid = threadIdx.x;
    __shared__ float part[THREADS];
    __shared__ float xs[SH];
    __shared__ int idx[SH];
    __shared__ int cnt;

    // x-build: (i, g) split; g strides over prev slices
    {
        const int i = tid % SH, g = tid / SH;
        float a = 0.f;
        for (int sp = g; sp < nsl_prev; sp += G)
            a += Pp[(long)sp * prev_K + h0 + i];
        part[g * SH + i] = a;
    }
    if (tid == 0) cnt = 0;
    __syncthreads();
    if (tid < SH) {
        float v = part[tid];
        #pragma unroll
        for (int g = 1; g < G; g++) v += part[g * SH + tid];
        v += bn[h0 + tid];
        if (RELU) v = fmaxf(v, 0.f);
        xs[tid] = v;
        if (v != 0.0f) { int p = atomicAdd(&cnt, 1); idx[p] = tid; }
    }
    __syncthreads();
    const int m = cnt;

    constexpr int TPR = TCOLS / 4;
    constexpr int RPI = THREADS / TPR;
    const int lane_r = tid % TPR;
    const int row_off = tid / TPR;
    const int c = blockIdx.x * TCOLS + 4 * lane_r;

    float ax = 0.f, ay = 0.f, az = 0.f, aw = 0.f;
    for (int j = row_off; j < m; j += RPI) {
        const int i = idx[j];
        const float4 w4 = *(const float4*)(Wn + (long)(h0 + i) * K + c);
        const float xv = xs[i];
        ax = fmaf(xv, w4.x, ax); ay = fmaf(xv, w4.y, ay);
        az = fmaf(xv, w4.z, az); aw = fmaf(xv, w4.w, aw);
    }
    if constexpr (RPI > 1) {
        __shared__ float red[THREADS * 4];
        red[tid * 4 + 0] = ax; red[tid * 4 + 1] = ay;
        red[tid * 4 + 2] = az; red[tid * 4 + 3] = aw;
        __syncthreads();
        if (row_off == 0) {
            #pragma unroll
            for (int g = 1; g < RPI; g++) {
                const int o = (tid + g * TPR) * 4;
                ax += red[o + 0]; ay += red[o + 1];
                az += red[o + 2]; aw += red[o + 3];
            }
            float4 r; r.x = ax; r.y = ay; r.z = az; r.w = aw;
            *(float4*)(Pn + c) = r;
        }
    } else {
        float4 r; r.x = ax; r.y = ay; r.z = az; r.w = aw;
        *(float4*)(Pn + c) = r;
    }
}

// ---------------------------------------------------------------------------
// W_t matvec with fused x-build:
// x[i] = sum_n ekq[n] * ( sum_{s<16} Pv[n][s][h0+i] + b_v[n,h0+i] )
// ekq[n] = bkq[n] + sum_j pkq[n*8+j].  SH=16, g == expert.
// ---------------------------------------------------------------------------
template<int TCOLS>
__global__ __launch_bounds__(THREADS) void matvec_tx(
    const float* __restrict__ Pv, const float* __restrict__ bv,
    const float* __restrict__ pkq, const float* __restrict__ bkq,
    const float* __restrict__ Wt, float* __restrict__ Pout,
    int K, int nsl_out)
{
    const int h0 = blockIdx.y * 16;
    const int tid = threadIdx.x;
    __shared__ float ekqs[16];
    __shared__ float part[THREADS];
    __shared__ float xs[16];

    if (tid < 16) {
        float e = bkq[tid];
        #pragma unroll
        for (int j = 0; j < 8; j++) e += pkq[tid * 8 + j];
        ekqs[tid] = e;
    }
    __syncthreads();
    {
        const int i = tid % 16, n = tid / 16;
        const float* Pp = Pv + (long)n * 16 * 2048;
        float a = 0.f;
        #pragma unroll
        for (int sp = 0; sp < 16; sp++) a += Pp[(long)sp * 2048 + h0 + i];
        a += bv[(long)n * 2048 + h0 + i];
        part[tid] = ekqs[n] * a;
    }
    __syncthreads();
    if (tid < 16) {
        float v = 0.f;
        #pragma unroll
        for (int g = 0; g < 16; g++) v += part[g * 16 + tid];
        xs[tid] = v;
    }
    __syncthreads();

    // dense main loop (TCOLS=1024: TPR=256, RPI=1)
    const int c = blockIdx.x * TCOLS + 4 * tid;
    float ax = 0.f, ay = 0.f, az = 0.f, aw = 0.f;
    #pragma unroll 4
    for (int i = 0; i < 16; i++) {
        const float4 w4 = *(const float4*)(Wt + (long)(h0 + i) * K + c);
        const float xv = xs[i];
        ax = fmaf(xv, w4.x, ax); ay = fmaf(xv, w4.y, ay);
        az = fmaf(xv, w4.z, az); aw = fmaf(xv, w4.w, aw);
    }
    float4 r; r.x = ax; r.y = ay; r.z = az; r.w = aw;
    *(float4*)(Pout + (long)blockIdx.y * K + c) = r;
}

// final: y[col] = sum_s P[s][col] + b[col]
template<bool RELU, bool HAS_BIAS>
__global__ __launch_bounds__(THREADS) void reduce_k(
    const float* __restrict__ P, const float* __restrict__ b,
    float* __restrict__ y, int K, int nslices)
{
    const int n = blockIdx.y;
    const int col = blockIdx.x * 64 + (threadIdx.x & 63);
    const int grp = threadIdx.x >> 6;
    const float* Pn = P + (long)n * nslices * K + col;
    float s = 0.f;
    for (int i = grp; i < nslices; i += 4) s += Pn[(long)i * K];
    __shared__ float red[4][64];
    red[grp][threadIdx.x & 63] = s;
    __syncthreads();
    if (threadIdx.x < 64) {
        float t = red[0][threadIdx.x] + red[1][threadIdx.x] +
                  red[2][threadIdx.x] + red[3][threadIdx.x];
        if (HAS_BIAS) t += b[(long)n * K + col];
        if (RELU) t = fmaxf(t, 0.f);
        y[(long)n * K + col] = t;
    }
}

// q[a] = W_q[t,t,a] + b_q[t,a]; bkq[n] = sum_a b_k[n,a]*q[a]
__global__ __launch_bounds__(THREADS) void qprep_k(
    const float* __restrict__ Wq, const float* __restrict__ bq,
    const float* __restrict__ bk, const int* __restrict__ task,
    float* __restrict__ q, float* __restrict__ bkq)
{
    const int tid = threadIdx.x;
    const int t = task[0];
    __shared__ float qs[256];
    float qv = Wq[((long)t * 10 + t) * 256 + tid] + bq[(long)t * 256 + tid];
    qs[tid] = qv; q[tid] = qv;
    __syncthreads();
    const int wave = tid >> 6, lane = tid & 63;
    for (int n = wave; n < 16; n += 4) {
        float s = 0.f;
        for (int a = lane; a < 256; a += 64) s += bk[n * 256 + a] * qs[a];
        for (int o = 32; o; o >>= 1) s += __shfl_down(s, o, 64);
        if (lane == 0) bkq[n] = s;
    }
}

// pkq[n*8+s] = sum_{h in 256-chunk s} eact[n,h] * (W_k[n,h,:] . q)
// eact built in-kernel from Pexp (32 slices) + b_exp + relu; rows skipped.
__global__ __launch_bounds__(THREADS) void kq2_k(
    const float* __restrict__ Pexp, const float* __restrict__ bexp,
    const float* __restrict__ Wk, const float* __restrict__ q,
    float* __restrict__ pkq)
{
    const int n = blockIdx.y, s = blockIdx.x;
    const int h0 = s * 256;
    const int tid = threadIdx.x;
    __shared__ float xs[256], qs[256];
    __shared__ int idx[256];
    __shared__ int cnt;
    __shared__ float wred[4];
    if (tid == 0) cnt = 0;
    qs[tid] = q[tid];
    const float* Pp = Pexp + (long)n * 32 * 2048;
    float a = 0.f;
    #pragma unroll 8
    for (int sp = 0; sp < 32; sp++) a += Pp[(long)sp * 2048 + h0 + tid];
    a += bexp[(long)n * 2048 + h0 + tid];
    a = fmaxf(a, 0.f);
    __syncthreads();
    xs[tid] = a;
    if (a != 0.0f) { int p = atomicAdd(&cnt, 1); idx[p] = tid; }
    __syncthreads();
    const int m = cnt;
    const int lane_r = tid & 63, row_off = tid >> 6;
    const float q0 = qs[4 * lane_r], q1 = qs[4 * lane_r + 1];
    const float q2 = qs[4 * lane_r + 2], q3 = qs[4 * lane_r + 3];
    float acc = 0.f;
    for (int j = row_off; j < m; j += 4) {
        const int i = idx[j];
        const float4 w4 = *(const float4*)(Wk + ((long)n * 2048 + h0 + i) * 256 + 4 * lane_r);
        acc += xs[i] * (w4.x * q0 + w4.y * q1 + w4.z * q2 + w4.w * q3);
    }
    for (int o = 32; o; o >>= 1) acc += __shfl_down(acc, o, 64);
    if ((tid & 63) == 0) wred[tid >> 6] = acc;
    __syncthreads();
    if (tid == 0) pkq[n * 8 + s] = wred[0] + wred[1] + wred[2] + wred[3];
}

extern "C" void kernel_launch(void* const* d_in, const int* in_sizes, int n_in,
                              void* d_out, int out_size, void* d_ws, size_t ws_size,
                              hipStream_t stream)
{
    const float* x    = (const float*)d_in[0];
    const float* W1   = (const float*)d_in[1];
    const float* b1   = (const float*)d_in[2];
    const float* W2   = (const float*)d_in[3];
    const float* b2   = (const float*)d_in[4];
    const float* Wexp = (const float*)d_in[5];
    const float* bexp = (const float*)d_in[6];
    const float* Wv   = (const float*)d_in[7];
    const float* bv   = (const float*)d_in[8];
    const float* Wk   = (const float*)d_in[9];
    const float* bk   = (const float*)d_in[10];
    const float* Wq   = (const float*)d_in[11];
    const float* bq   = (const float*)d_in[12];
    const float* Wt   = (const float*)d_in[13];
    const float* bt   = (const float*)d_in[14];
    const float* Wl   = (const float*)d_in[15];
    const float* bl   = (const float*)d_in[16];
    const int*   task = (const int*)d_in[17];

    // workspace layout (floats) — all written before read
    float* ws   = (float*)d_ws;
    float* P1   = ws;             // 128*2048  = 262144
    float* P2   = ws + 262144;    // 128*2048  = 262144
    float* Pexp = ws + 524288;    // 16*32*2048 = 1048576
    float* Pv   = ws + 1572864;   // 16*16*2048 = 524288
    float* Pt   = ws + 2097152;   // 128*2048  = 262144
    float* Pl   = ws + 2359296;   // 64*512    = 32768
    float* q    = ws + 2392064;   // 256
    float* bkq  = ws + 2392320;   // 16
    float* pkq  = ws + 2392336;   // 128

    // q / b_k.q prep
    qprep_k<<<1, 256, 0, stream>>>(Wq, bq, bk, task, q, bkq);

    // P1 = partials of x @ W1                        (16 MB dense)
    matvec_k<1024><<<dim3(2, 128, 1), THREADS, 16 * 8, stream>>>(
        x, W1, P1, 2048, 16, 128, 0, 0);

    // P2 = partials of relu(red(P1)+b1) @ W2         (~8 MB)
    matvec_rx<1024, 16, true><<<dim3(2, 128, 1), THREADS, 0, stream>>>(
        P1, b1, W2, P2, 2048, 128, 2048, 128, 0, 0, 0);

    // Pexp[n] = partials of relu(red(P2)+b2) @ W_exp[n]   (~128 MB)
    matvec_rx<1024, 64, true><<<dim3(2, 32, 16), THREADS, 0, stream>>>(
        P2, b2, Wexp, Pexp, 2048, 128, 2048, 32, 0, 0, 2048L * 2048);

    // pkq = partials of eact . (W_k . q)             (~16 MB)
    kq2_k<<<dim3(8, 16), THREADS, 0, stream>>>(Pexp, bexp, Wk, q, pkq);

    // Pv[n] = partials of eact[n] @ W_v[n]  (no ekq yet)   (~128 MB)
    matvec_rx<1024, 128, true><<<dim3(2, 16, 16), THREADS, 0, stream>>>(
        Pexp, bexp, Wv, Pv, 2048, 32, 2048, 16,
        32L * 2048, 2048, 2048L * 2048);

    // Pt = partials of (sum_n ekq[n]*(red(Pv[n])+bv[n])) @ W_t   (16 MB dense)
    matvec_tx<1024><<<dim3(2, 128, 1), THREADS, 0, stream>>>(
        Pv, bv, pkq, bkq, Wt, Pt, 2048, 128);

    // Pl = partials of relu(red(Pt)+bt) @ W_l        (~2 MB)
    matvec_rx<512, 32, true><<<dim3(1, 64, 1), THREADS, 0, stream>>>(
        Pt, bt, Wl, Pl, 512, 128, 2048, 64, 0, 0, 0);

    // d_out = red(Pl) + bl
    reduce_k<false, true><<<dim3(8, 1), THREADS, 0, stream>>>(
        Pl, bl, (float*)d_out, 512, 64);
}